// Round 2
// baseline (472.943 us; speedup 1.0000x reference)
//
#include <hip/hip_runtime.h>

// SparseMinCostFlow — 2-launch, column-bucketed flow chain.
// N=8192, E=262144, 10 iterations, dense NxN fp32 out (256 MB).
//
// r1-r5 invariant (prev session): no global atomics in the iteration chain.
// This round: kill the partial-matrix exchange. Edges are counting-sorted
// once by col>>8 into 32 buckets (packed u64 = row | coff<<13 | f32bits<<32),
// so flow block b OWNS cols [b*256, b*256+256):
//   per stage: read full adj (32KB, u64 pairs) + own bucket (64KB packed)
//              -> LDS-accumulate 256-word slice -> write 1KB slice
//   ONE flag barrier per stage (was: 1MB flush + 2 barriers + 1MB reduce).
// Sorted edges live in the LAST 2MB of out (zeroed by flow team at the end),
// so ws footprint is ~330KB.
//
// Launch 1: fused_flow_zero (512 x 1024, 2/CU):
//   blocks 0..31  : sort (2 barriers) + 9 stages (8 barriers) + done barrier
//   blocks 32..511: zero out[0 .. N4T) with nontemporal float4 stores
// Launch 2: scatter_final: out[r*N+c] += values[e] * adj9f[rows[e]]  (unchanged)

#define NN 8192
#define EE 262144
#define FBLK 32
#define TOTBLK 512
#define ZBLK (TOTBLK - FBLK)
#define THREADS 1024
#define EPB (EE / FBLK)          // 8192 edges per flow block (pre-sort chunk)
#define SLICE (NN / FBLK)        // 256 cols owned per flow block
#define HSLICE (SLICE / 2)       // 128 u64 words per adj slice
#define HN (NN / 2)              // 4096 u64 words per adj vector
#define N4 ((long)NN * NN / 4)   // float4 count in output
#define SE_F4 ((long)EE / 2)     // sorted-edge area = EE*8B = EE/2 float4
#define N4T (N4 - SE_F4)         // zero-team range (flow team zeroes the tail)
#define MAGIC 0x5CA1AB1Eu        // != 0xAAAAAAAA ws poison, != 0

typedef float ntf4 __attribute__((ext_vector_type(4)));   // nontemporal-store-able

#define LOAD_AU(p)    __hip_atomic_load((p),  __ATOMIC_RELAXED, __HIP_MEMORY_SCOPE_AGENT)
#define STORE_AU(p,v) __hip_atomic_store((p), (v), __ATOMIC_RELAXED, __HIP_MEMORY_SCOPE_AGENT)

// All-flow-blocks barrier: own-word flag store + one polling wave.
// Caller must __syncthreads() first (drains vmcnt: data ahead of flag).
__device__ __forceinline__ void flag_barrier(unsigned* fl, int bid, int tid) {
    if (tid == 0) STORE_AU(&fl[bid], MAGIC);
    asm volatile("" ::: "memory");
    if (tid < 64) {
        for (;;) {
            unsigned f = (tid < FBLK) ? LOAD_AU(&fl[tid]) : MAGIC;
            if (__all(f == MAGIC)) break;
            __builtin_amdgcn_s_sleep(2);
        }
    }
    asm volatile("" ::: "memory");
    __syncthreads();
}

__global__ void __launch_bounds__(THREADS, 8) fused_flow_zero(
        const float* __restrict__ values, const float* __restrict__ dem,
        const int* __restrict__ rows, const int* __restrict__ cols,
        unsigned long long* __restrict__ adjp,   // 9 * HN u64 (slots 1..8 used)
        float* __restrict__ adj9f,               // NN floats (read by launch 2)
        unsigned* __restrict__ cnt,              // FBLK*FBLK block-x-bucket counts
        unsigned* __restrict__ flags,            // 12 * 64 words
        unsigned long long* __restrict__ se,     // EE packed edges (in out-tail)
        float4* __restrict__ out4) {
    __shared__ float    adjLDS[NN];              // 32 KB
    __shared__ float    accLDS[SLICE];
    __shared__ float    demLDS[SLICE];
    __shared__ unsigned cntLDS[FBLK * FBLK];     // 4 KB
    __shared__ unsigned histLDS[FBLK];           // S1 histogram / S2 totals
    __shared__ unsigned bstartLDS[FBLK + 1];
    __shared__ unsigned offsLDS[FBLK];           // live sort cursors
    __shared__ unsigned rangeLDS[2];             // my bucket [bs, be)
    const int bid = blockIdx.x;
    const int tid = threadIdx.x;

    if (bid < FBLK) {
        // ================= flow team =================
        // ---- S1: histogram my 8192-edge chunk by bucket = col>>8 ----
        if (tid < FBLK) histLDS[tid] = 0;
        __syncthreads();
        {
            const int4* c4 = (const int4*)(cols + bid * EPB);
            int4 a = c4[2 * tid], b = c4[2 * tid + 1];
            atomicAdd(&histLDS[a.x >> 8], 1u);
            atomicAdd(&histLDS[a.y >> 8], 1u);
            atomicAdd(&histLDS[a.z >> 8], 1u);
            atomicAdd(&histLDS[a.w >> 8], 1u);
            atomicAdd(&histLDS[b.x >> 8], 1u);
            atomicAdd(&histLDS[b.y >> 8], 1u);
            atomicAdd(&histLDS[b.z >> 8], 1u);
            atomicAdd(&histLDS[b.w >> 8], 1u);
        }
        __syncthreads();
        if (tid < FBLK) STORE_AU(&cnt[bid * FBLK + tid], histLDS[tid]);
        __syncthreads();                          // drain cnt stores
        flag_barrier(flags + 0 * 64, bid, tid);   // B0: all counts visible

        // ---- S2: full count matrix -> my sort cursors + my bucket range ----
        cntLDS[tid] = LOAD_AU(&cnt[tid]);         // FBLK*FBLK == THREADS
        __syncthreads();
        if (tid < FBLK) {                         // bucket totals
            unsigned tot = 0;
            for (int b = 0; b < FBLK; ++b) tot += cntLDS[b * FBLK + tid];
            histLDS[tid] = tot;
        }
        __syncthreads();
        if (tid == 0) {                           // exclusive scan of totals
            unsigned run = 0;
            for (int k = 0; k < FBLK; ++k) { bstartLDS[k] = run; run += histLDS[k]; }
            bstartLDS[FBLK] = run;                // == EE
        }
        __syncthreads();
        if (tid < FBLK) {                         // offs(bid,k) = bstart[k] + sum_{b<bid} cnt[b][k]
            unsigned off = bstartLDS[tid];
            for (int b = 0; b < bid; ++b) off += cntLDS[b * FBLK + tid];
            offsLDS[tid] = off;
        }
        if (tid == 0) { rangeLDS[0] = bstartLDS[bid]; rangeLDS[1] = bstartLDS[bid + 1]; }
        __syncthreads();

        // ---- S3: scatter my chunk into bucket-sorted packed array ----
        {
            const int4*   r4 = (const int4*)(rows + bid * EPB);
            const int4*   c4 = (const int4*)(cols + bid * EPB);
            const float4* v4 = (const float4*)(values + bid * EPB);
            int4 ra = r4[2 * tid], rb = r4[2 * tid + 1];
            int4 ca = c4[2 * tid], cb = c4[2 * tid + 1];
            float4 va = v4[2 * tid], vb = v4[2 * tid + 1];
            #define SORT_PUSH(R, C, V) do {                                          \
                int k_ = (C) >> 8;                                                   \
                unsigned dst_ = atomicAdd(&offsLDS[k_], 1u);                         \
                unsigned long long w_ = (unsigned)((R) | (((C) & 255) << 13))        \
                                      | ((unsigned long long)__float_as_uint(V) << 32); \
                STORE_AU(&se[dst_], w_);                                             \
            } while (0)
            SORT_PUSH(ra.x, ca.x, va.x);  SORT_PUSH(ra.y, ca.y, va.y);
            SORT_PUSH(ra.z, ca.z, va.z);  SORT_PUSH(ra.w, ca.w, va.w);
            SORT_PUSH(rb.x, cb.x, vb.x);  SORT_PUSH(rb.y, cb.y, vb.y);
            SORT_PUSH(rb.z, cb.z, vb.z);  SORT_PUSH(rb.w, cb.w, vb.w);
            #undef SORT_PUSH
        }
        __syncthreads();                          // drain se stores
        flag_barrier(flags + 1 * 64, bid, tid);   // B1: sorted edges visible

        const int bs = (int)rangeLDS[0];
        const int be = (int)rangeLDS[1];
        if (tid < SLICE) demLDS[tid] = dem[bid * SLICE + tid];

        // ---- 9 stages: adj_{s+1} = relu(A^T_col (v*adj_s[row]) - d) ----
        for (int s = 1; s <= 9; ++s) {
            if (s == 1) {                         // adj1 = relu(0 - d)
                #pragma unroll
                for (int j = 0; j < NN / THREADS; ++j) {
                    int c = tid + j * THREADS;
                    adjLDS[c] = fmaxf(-dem[c], 0.f);
                }
            } else {                              // adj_s from u64 pairs
                const unsigned long long* ap = adjp + (size_t)(s - 1) * HN;
                #pragma unroll
                for (int j = 0; j < HN / THREADS; ++j) {
                    int i = tid + j * THREADS;
                    unsigned long long w = LOAD_AU(&ap[i]);
                    adjLDS[2 * i]     = __uint_as_float((unsigned)w);
                    adjLDS[2 * i + 1] = __uint_as_float((unsigned)(w >> 32));
                }
            }
            if (tid < SLICE) accLDS[tid] = 0.f;
            __syncthreads();

            // my bucket's edges: one u64 load each. Predicated unroll keeps
            // 9 loads in flight; OOB lanes add +0.0f to acc[0] (harmless).
            #pragma unroll
            for (int j = 0; j < 9; ++j) {
                int i = bs + tid + (j << 10);
                unsigned long long w = (i < be) ? LOAD_AU(&se[i]) : 0ull;
                unsigned meta = (unsigned)w;
                float v = __uint_as_float((unsigned)(w >> 32));
                atomicAdd(&accLDS[(meta >> 13) & 255], v * adjLDS[meta & (NN - 1)]);
            }
            for (int i = bs + tid + 9 * THREADS; i < be; i += THREADS) { // safety tail
                unsigned long long w = LOAD_AU(&se[i]);
                unsigned meta = (unsigned)w;
                float v = __uint_as_float((unsigned)(w >> 32));
                atomicAdd(&accLDS[(meta >> 13) & 255], v * adjLDS[meta & (NN - 1)]);
            }
            __syncthreads();

            if (s < 9) {
                if (tid < SLICE) accLDS[tid] = fmaxf(accLDS[tid] - demLDS[tid], 0.f);
                __syncthreads();
                if (tid < HSLICE) {               // pack pairs, write my 1KB slice
                    unsigned long long w =
                        ((unsigned long long)__float_as_uint(accLDS[2 * tid + 1]) << 32)
                      | __float_as_uint(accLDS[2 * tid]);
                    STORE_AU(&adjp[(size_t)s * HN + bid * HSLICE + tid], w);
                }
                __syncthreads();                  // drain slice stores
                flag_barrier(flags + (1 + s) * 64, bid, tid);   // lines 2..9
            } else {
                if (tid < SLICE)
                    STORE_AU(&adj9f[bid * SLICE + tid],
                             fmaxf(accLDS[tid] - demLDS[tid], 0.f));
                __syncthreads();
                flag_barrier(flags + 10 * 64, bid, tid);  // all stage-9 se reads done
                // zero the sorted-edge tail of out (2MB across 32 blocks)
                const float4 z = make_float4(0.f, 0.f, 0.f, 0.f);
                #pragma unroll
                for (int j = 0; j < 4; ++j)
                    out4[N4T + (long)bid * 4096 + j * THREADS + tid] = z;
            }
        }
    } else {
        // ================= zero team: clear out[0 .. N4T) =================
        long i = (long)(bid - FBLK) * THREADS + tid;
        const long stride = (long)ZBLK * THREADS;
        const ntf4 z = (ntf4)(0.f);
        ntf4* o = (ntf4*)out4;
        for (; i < N4T; i += stride)
            __builtin_nontemporal_store(z, o + i);
    }
}

__global__ void __launch_bounds__(256) scatter_final(
        const float* __restrict__ values,
        const int* __restrict__ rows, const int* __restrict__ cols,
        const float* __restrict__ adj9, float* __restrict__ out) {
    int e = blockIdx.x * 256 + threadIdx.x;
    int r = rows[e];
    float a = adj9[r];                       // plain load: 32 KB, L1-resident
    atomicAdd(&out[(long)r * NN + cols[e]], values[e] * a);
}

extern "C" void kernel_launch(void* const* d_in, const int* in_sizes, int n_in,
                              void* d_out, int out_size, void* d_ws, size_t ws_size,
                              hipStream_t stream) {
    const float* values = (const float*)d_in[0];
    const float* dem    = (const float*)d_in[1];
    const int*   rows   = (const int*)d_in[2];
    const int*   cols   = (const int*)d_in[3];
    float* out = (float*)d_out;

    unsigned long long* adjp  = (unsigned long long*)d_ws;        // 288 KB
    float*              adj9f = (float*)(adjp + 9L * HN);         // 32 KB
    unsigned*           cnt   = (unsigned*)(adj9f + NN);          // 4 KB
    unsigned*           flags = cnt + FBLK * FBLK;                // 3 KB
    unsigned long long* se    = (unsigned long long*)((float4*)d_out + N4T); // out tail, 2 MB

    fused_flow_zero<<<TOTBLK, THREADS, 0, stream>>>(
        values, dem, rows, cols, adjp, adj9f, cnt, flags, se, (float4*)out);

    scatter_final<<<EE / 256, 256, 0, stream>>>(
        values, rows, cols, adj9f, out);
}

// Round 3
// 419.638 us; speedup vs baseline: 1.1270x; 1.1270x over previous
//
#include <hip/hip_runtime.h>

// SparseMinCostFlow — 2-launch, column-bucketed flow chain, EDGES IN REGISTERS.
// N=8192, E=262144, 10 iterations, dense NxN fp32 out (256 MB).
//
// Accounting (r0/r2): dur_us = harness ws-poison fill (~199us, fixed) + fused
// + scatter. The fused tail is the 32-block flow chain (~20us/stage in r2).
// r2 lesson: per-stage cross-block TRAFFIC isn't the cost — r0 (2MB/stage) and
// r2 (96KB/stage) both ran ~19-20us/stage. Remaining per-stage costs: 64KB
// agent-scope edge reloads (L2-bypass latency), 32KB adj load, flag barrier.
// This round: edges are stage-INVARIANT -> load once into 18 VGPRs after the
// sort; per stage only adj(32KB) + ~256 LDS wave-ops + 1KB publish + barrier.
//
// Sort (once): counting-sort edges by col>>8 into 32 buckets (packed u64 =
// row | coff<<13 | f32bits<<32); block b owns cols [b*256,(b+1)*256).
// Zero team: plain (cached) float4 stores — leaves lines L2-warm for scatter
// (r2: NT zeroing made scatter 30->74us; reverted).
// se/flags/adjp all in ws; output stays pure.

#define NN 8192
#define EE 262144
#define FBLK 32
#define TOTBLK 512
#define ZBLK (TOTBLK - FBLK)
#define THREADS 1024
#define EPB (EE / FBLK)          // 8192 edges per flow block (pre-sort chunk)
#define SLICE (NN / FBLK)        // 256 cols owned per flow block
#define HSLICE (SLICE / 2)       // 128 u64 words per adj slice
#define HN (NN / 2)              // 4096 u64 words per adj vector
#define N4 ((long)NN * NN / 4)   // float4 count in output
#define EREG 9                   // register-resident edges per thread
#define MAGIC 0x5CA1AB1Eu        // != 0xAAAAAAAA ws poison, != 0

#define LOAD_AU(p)    __hip_atomic_load((p),  __ATOMIC_RELAXED, __HIP_MEMORY_SCOPE_AGENT)
#define STORE_AU(p,v) __hip_atomic_store((p), (v), __ATOMIC_RELAXED, __HIP_MEMORY_SCOPE_AGENT)

// All-flow-blocks barrier: own-word flag store + one polling wave.
// Caller must __syncthreads() first (drains vmcnt: data ahead of flag).
__device__ __forceinline__ void flag_barrier(unsigned* fl, int bid, int tid) {
    if (tid == 0) STORE_AU(&fl[bid], MAGIC);
    asm volatile("" ::: "memory");
    if (tid < 64) {
        for (;;) {
            unsigned f = (tid < FBLK) ? LOAD_AU(&fl[tid]) : MAGIC;
            if (__all(f == MAGIC)) break;
            __builtin_amdgcn_s_sleep(2);
        }
    }
    asm volatile("" ::: "memory");
    __syncthreads();
}

__global__ void __launch_bounds__(THREADS, 4) fused_flow_zero(
        const float* __restrict__ values, const float* __restrict__ dem,
        const int* __restrict__ rows, const int* __restrict__ cols,
        unsigned long long* __restrict__ se,     // EE packed sorted edges (ws)
        unsigned long long* __restrict__ adjp,   // 9 * HN u64 (slots 1..8 used)
        float* __restrict__ adj9f,               // NN floats (read by launch 2)
        unsigned* __restrict__ cnt,              // FBLK*FBLK block-x-bucket counts
        unsigned* __restrict__ flags,            // 10 * 64 words
        float4* __restrict__ out4) {
    __shared__ float    adjLDS[NN];              // 32 KB
    __shared__ float    accLDS[SLICE];
    __shared__ float    demLDS[SLICE];
    __shared__ unsigned cntLDS[FBLK * FBLK];     // 4 KB
    __shared__ unsigned histLDS[FBLK];
    __shared__ unsigned bstartLDS[FBLK + 1];
    __shared__ unsigned offsLDS[FBLK];
    __shared__ unsigned rangeLDS[2];
    const int bid = blockIdx.x;
    const int tid = threadIdx.x;

    if (bid < FBLK) {
        // ================= flow team =================
        // ---- S1: histogram my 8192-edge chunk by bucket = col>>8 ----
        if (tid < FBLK) histLDS[tid] = 0;
        __syncthreads();
        {
            const int4* c4 = (const int4*)(cols + bid * EPB);
            int4 a = c4[2 * tid], b = c4[2 * tid + 1];
            atomicAdd(&histLDS[a.x >> 8], 1u);
            atomicAdd(&histLDS[a.y >> 8], 1u);
            atomicAdd(&histLDS[a.z >> 8], 1u);
            atomicAdd(&histLDS[a.w >> 8], 1u);
            atomicAdd(&histLDS[b.x >> 8], 1u);
            atomicAdd(&histLDS[b.y >> 8], 1u);
            atomicAdd(&histLDS[b.z >> 8], 1u);
            atomicAdd(&histLDS[b.w >> 8], 1u);
        }
        __syncthreads();
        if (tid < FBLK) STORE_AU(&cnt[bid * FBLK + tid], histLDS[tid]);
        __syncthreads();                          // drain cnt stores
        flag_barrier(flags + 0 * 64, bid, tid);   // B0: all counts visible

        // ---- S2: full count matrix -> sort cursors + my bucket range ----
        cntLDS[tid] = LOAD_AU(&cnt[tid]);         // FBLK*FBLK == THREADS
        __syncthreads();
        if (tid < FBLK) {                         // bucket totals
            unsigned tot = 0;
            for (int b = 0; b < FBLK; ++b) tot += cntLDS[b * FBLK + tid];
            histLDS[tid] = tot;
        }
        __syncthreads();
        if (tid == 0) {                           // exclusive scan of totals
            unsigned run = 0;
            for (int k = 0; k < FBLK; ++k) { bstartLDS[k] = run; run += histLDS[k]; }
            bstartLDS[FBLK] = run;                // == EE
        }
        __syncthreads();
        if (tid < FBLK) {                         // offs(bid,k)
            unsigned off = bstartLDS[tid];
            for (int b = 0; b < bid; ++b) off += cntLDS[b * FBLK + tid];
            offsLDS[tid] = off;
        }
        if (tid == 0) { rangeLDS[0] = bstartLDS[bid]; rangeLDS[1] = bstartLDS[bid + 1]; }
        __syncthreads();

        // ---- S3: scatter my chunk into bucket-sorted packed array ----
        {
            const int4*   r4 = (const int4*)(rows + bid * EPB);
            const int4*   c4 = (const int4*)(cols + bid * EPB);
            const float4* v4 = (const float4*)(values + bid * EPB);
            int4 ra = r4[2 * tid], rb = r4[2 * tid + 1];
            int4 ca = c4[2 * tid], cb = c4[2 * tid + 1];
            float4 va = v4[2 * tid], vb = v4[2 * tid + 1];
            #define SORT_PUSH(R, C, V) do {                                          \
                int k_ = (C) >> 8;                                                   \
                unsigned dst_ = atomicAdd(&offsLDS[k_], 1u);                         \
                unsigned long long w_ = (unsigned)((R) | (((C) & 255) << 13))        \
                                      | ((unsigned long long)__float_as_uint(V) << 32); \
                STORE_AU(&se[dst_], w_);                                             \
            } while (0)
            SORT_PUSH(ra.x, ca.x, va.x);  SORT_PUSH(ra.y, ca.y, va.y);
            SORT_PUSH(ra.z, ca.z, va.z);  SORT_PUSH(ra.w, ca.w, va.w);
            SORT_PUSH(rb.x, cb.x, vb.x);  SORT_PUSH(rb.y, cb.y, vb.y);
            SORT_PUSH(rb.z, cb.z, vb.z);  SORT_PUSH(rb.w, cb.w, vb.w);
            #undef SORT_PUSH
        }
        __syncthreads();                          // drain se stores
        flag_barrier(flags + 1 * 64, bid, tid);   // B1: sorted edges visible

        const int bs = (int)rangeLDS[0];
        const int be = (int)rangeLDS[1];
        if (tid < SLICE) demLDS[tid] = dem[bid * SLICE + tid];

        // ---- load my bucket's edges into registers, ONCE ----
        unsigned long long ereg[EREG];
        #pragma unroll
        for (int j = 0; j < EREG; ++j) {
            int i = bs + tid + (j << 10);
            ereg[j] = (i < be) ? LOAD_AU(&se[i]) : 0ull;   // 0 => +0.0f to acc[0]
        }

        // ---- 9 stages: adj_{s+1} = relu(A^T_col (v*adj_s[row]) - d) ----
        for (int s = 1; s <= 9; ++s) {
            if (s == 1) {                         // adj1 = relu(0 - d)
                #pragma unroll
                for (int j = 0; j < NN / THREADS; ++j) {
                    int c = tid + j * THREADS;
                    adjLDS[c] = fmaxf(-dem[c], 0.f);
                }
            } else {                              // adj_s from u64 pairs
                const unsigned long long* ap = adjp + (size_t)(s - 1) * HN;
                #pragma unroll
                for (int j = 0; j < HN / THREADS; ++j) {
                    int i = tid + j * THREADS;
                    unsigned long long w = LOAD_AU(&ap[i]);
                    adjLDS[2 * i]     = __uint_as_float((unsigned)w);
                    adjLDS[2 * i + 1] = __uint_as_float((unsigned)(w >> 32));
                }
            }
            if (tid < SLICE) accLDS[tid] = 0.f;
            __syncthreads();

            // register-resident edges: zero global loads in steady state
            #pragma unroll
            for (int j = 0; j < EREG; ++j) {
                unsigned meta = (unsigned)ereg[j];
                float v = __uint_as_float((unsigned)(ereg[j] >> 32));
                atomicAdd(&accLDS[(meta >> 13) & 255], v * adjLDS[meta & (NN - 1)]);
            }
            for (int i = bs + tid + EREG * THREADS; i < be; i += THREADS) { // ~never
                unsigned long long w = LOAD_AU(&se[i]);
                unsigned meta = (unsigned)w;
                float v = __uint_as_float((unsigned)(w >> 32));
                atomicAdd(&accLDS[(meta >> 13) & 255], v * adjLDS[meta & (NN - 1)]);
            }
            __syncthreads();

            if (s < 9) {
                if (tid < HSLICE) {               // fused relu + pack + publish
                    float lo = fmaxf(accLDS[2 * tid]     - demLDS[2 * tid],     0.f);
                    float hi = fmaxf(accLDS[2 * tid + 1] - demLDS[2 * tid + 1], 0.f);
                    unsigned long long w =
                        ((unsigned long long)__float_as_uint(hi) << 32)
                      | __float_as_uint(lo);
                    STORE_AU(&adjp[(size_t)s * HN + bid * HSLICE + tid], w);
                }
                __syncthreads();                  // drain slice stores
                flag_barrier(flags + (1 + s) * 64, bid, tid);
            } else {
                if (tid < SLICE)
                    STORE_AU(&adj9f[bid * SLICE + tid],
                             fmaxf(accLDS[tid] - demLDS[tid], 0.f));
                // no barrier: dispatch boundary orders adj9f for launch 2
            }
        }
    } else {
        // ====== zero team: clear out (plain stores -> L2-warm for scatter) ======
        long i = (long)(bid - FBLK) * THREADS + tid;
        const long stride = (long)ZBLK * THREADS;
        const float4 z = make_float4(0.f, 0.f, 0.f, 0.f);
        for (; i < N4; i += stride) out4[i] = z;
    }
}

__global__ void __launch_bounds__(256) scatter_final(
        const float* __restrict__ values,
        const int* __restrict__ rows, const int* __restrict__ cols,
        const float* __restrict__ adj9, float* __restrict__ out) {
    int e = blockIdx.x * 256 + threadIdx.x;
    int r = rows[e];
    float a = adj9[r];                       // plain load: 32 KB, L1-resident
    atomicAdd(&out[(long)r * NN + cols[e]], values[e] * a);
}

extern "C" void kernel_launch(void* const* d_in, const int* in_sizes, int n_in,
                              void* d_out, int out_size, void* d_ws, size_t ws_size,
                              hipStream_t stream) {
    const float* values = (const float*)d_in[0];
    const float* dem    = (const float*)d_in[1];
    const int*   rows   = (const int*)d_in[2];
    const int*   cols   = (const int*)d_in[3];
    float* out = (float*)d_out;

    unsigned long long* se    = (unsigned long long*)d_ws;        // 2 MB
    unsigned long long* adjp  = se + (long)EE;                    // 288 KB
    float*              adj9f = (float*)(adjp + 9L * HN);         // 32 KB
    unsigned*           cnt   = (unsigned*)(adj9f + NN);          // 4 KB
    unsigned*           flags = cnt + FBLK * FBLK;                // 2.5 KB

    fused_flow_zero<<<TOTBLK, THREADS, 0, stream>>>(
        values, dem, rows, cols, se, adjp, adj9f, cnt, flags, (float4*)out);

    scatter_final<<<EE / 256, 256, 0, stream>>>(
        values, rows, cols, adj9f, out);
}